// Round 16
// baseline (632.042 us; speedup 1.0000x reference)
//
#include <hip/hip_runtime.h>
#include <hip/hip_bf16.h>
#include <cstdint>

typedef unsigned short u16;
typedef unsigned int u32;
typedef __bf16 bf16_t;
typedef bf16_t bf16x8 __attribute__((ext_vector_type(8)));
typedef float f32x4 __attribute__((ext_vector_type(4)));

// Problem constants
constexpr int Bn = 2, Sn = 1024, Dn = 512, Hn = 8, Cn = 64, DHn = 64, ROTn = 32;
constexpr int MLPn = 1024, OUTn = 32000;
constexpr int NCH = 32;
constexpr int CSs = Sn / NCH;
constexpr float SCALE = 0.125f;
constexpr float EPSf = 1e-5f;
constexpr int QKVW = 1536;   // fused qkv row width
constexpr int KVW = 1024;    // fused vdk|vdv row width

__device__ __forceinline__ u16 f2b(float x) {  // fp32 -> bf16 bits, RNE
  u32 u = __float_as_uint(x);
  u32 r = (u + 0x7FFFu + ((u >> 16) & 1u)) >> 16;
  return (u16)r;
}

// ---------------------------------------------------------------------------
// Embedding gather + LayerNorm; writes fp32 and bf16
// ---------------------------------------------------------------------------
__global__ __launch_bounds__(256) void embed_ln_kernel(
    const int* __restrict__ tokens, const float* __restrict__ emb,
    const float* __restrict__ g, const float* __restrict__ bb,
    float* __restrict__ out, u16* __restrict__ out16) {
  int row = blockIdx.x;
  int tid = threadIdx.x;
  int tok = tokens[row];
  const float* src = emb + (size_t)tok * Dn;
  __shared__ float red[256];
  float v0 = src[tid], v1 = src[tid + 256];
  red[tid] = v0 + v1;
  __syncthreads();
  for (int s = 128; s > 0; s >>= 1) { if (tid < s) red[tid] += red[tid + s]; __syncthreads(); }
  float mean = red[0] * (1.0f / Dn);
  __syncthreads();
  float d0 = v0 - mean, d1 = v1 - mean;
  red[tid] = d0 * d0 + d1 * d1;
  __syncthreads();
  for (int s = 128; s > 0; s >>= 1) { if (tid < s) red[tid] += red[tid + s]; __syncthreads(); }
  float rstd = rsqrtf(red[0] * (1.0f / Dn) + EPSf);
  float o0 = d0 * rstd * g[tid] + bb[tid];
  float o1 = d1 * rstd * g[tid + 256] + bb[tid + 256];
  float* dst = out + (size_t)row * Dn;
  dst[tid] = o0; dst[tid + 256] = o1;
  u16* dst16 = out16 + (size_t)row * Dn;
  dst16[tid] = f2b(o0); dst16[tid + 256] = f2b(o1);
}

// LayerNorm of (x [+ res]) -> out (fp32) and out16 (bf16, optional)
__global__ __launch_bounds__(256) void ln_kernel(
    const float* __restrict__ x, const float* __restrict__ res,
    const float* __restrict__ g, const float* __restrict__ bb,
    float* __restrict__ out, u16* __restrict__ out16) {
  int row = blockIdx.x;
  int tid = threadIdx.x;
  const float* xr = x + (size_t)row * Dn;
  float v0 = xr[tid], v1 = xr[tid + 256];
  if (res) {
    const float* rr = res + (size_t)row * Dn;
    v0 += rr[tid]; v1 += rr[tid + 256];
  }
  __shared__ float red[256];
  red[tid] = v0 + v1;
  __syncthreads();
  for (int s = 128; s > 0; s >>= 1) { if (tid < s) red[tid] += red[tid + s]; __syncthreads(); }
  float mean = red[0] * (1.0f / Dn);
  __syncthreads();
  float d0 = v0 - mean, d1 = v1 - mean;
  red[tid] = d0 * d0 + d1 * d1;
  __syncthreads();
  for (int s = 128; s > 0; s >>= 1) { if (tid < s) red[tid] += red[tid + s]; __syncthreads(); }
  float rstd = rsqrtf(red[0] * (1.0f / Dn) + EPSf);
  float o0 = d0 * rstd * g[tid] + bb[tid];
  float o1 = d1 * rstd * g[tid + 256] + bb[tid + 256];
  float* dst = out + (size_t)row * Dn;
  dst[tid] = o0; dst[tid + 256] = o1;
  if (out16) {
    u16* dst16 = out16 + (size_t)row * Dn;
    dst16[tid] = f2b(o0); dst16[tid + 256] = f2b(o1);
  }
}

// ---------------------------------------------------------------------------
// Merged weight prep: 6 transposes (fp32 [K][N] -> bf16 [N][K]) + bias concat.
// ---------------------------------------------------------------------------
__global__ __launch_bounds__(256) void prep_weights_kernel(
    const float* __restrict__ Wq, const float* __restrict__ Wk,
    const float* __restrict__ Wv, const float* __restrict__ Wo,
    const float* __restrict__ W1, const float* __restrict__ W2,
    u16* __restrict__ WqkvT, u16* __restrict__ WoT,
    u16* __restrict__ W1T, u16* __restrict__ W2T,
    const float* __restrict__ bq, const float* __restrict__ bk,
    const float* __restrict__ bv, float* __restrict__ bqkv) {
  int bid = blockIdx.x;
  int t = threadIdx.x;
  if (bid == 512) {
    for (int i = t; i < 512; i += 256) {
      bqkv[i] = bq[i]; bqkv[512 + i] = bk[i]; bqkv[1024 + i] = bv[i];
    }
    return;
  }
  const float* W; u16* Wt; int K, N, tile, nbx;
  if (bid < 64)       { W = Wq; Wt = WqkvT;              K = 512;  N = 512;  tile = bid;       nbx = 8;  }
  else if (bid < 128) { W = Wk; Wt = WqkvT + 512 * 512;  K = 512;  N = 512;  tile = bid - 64;  nbx = 8;  }
  else if (bid < 192) { W = Wv; Wt = WqkvT + 1024 * 512; K = 512;  N = 512;  tile = bid - 128; nbx = 8;  }
  else if (bid < 256) { W = Wo; Wt = WoT;                K = 512;  N = 512;  tile = bid - 192; nbx = 8;  }
  else if (bid < 384) { W = W1; Wt = W1T;                K = 512;  N = 1024; tile = bid - 256; nbx = 16; }
  else                { W = W2; Wt = W2T;                K = 1024; N = 512;  tile = bid - 384; nbx = 8;  }
  int n0 = (tile % nbx) * 64, k0 = (tile / nbx) * 64;

  __shared__ float tilebuf[64][65];
  int kr = t >> 4;
  int nc = (t & 15) * 4;
#pragma unroll
  for (int i = 0; i < 4; i++) {
    float4 v = *(const float4*)(W + (size_t)(k0 + kr + i * 16) * N + n0 + nc);
    tilebuf[kr + i * 16][nc] = v.x; tilebuf[kr + i * 16][nc + 1] = v.y;
    tilebuf[kr + i * 16][nc + 2] = v.z; tilebuf[kr + i * 16][nc + 3] = v.w;
  }
  __syncthreads();
  int n = t >> 2;
  int kb = (t & 3) * 16;
  u16 tmp[16];
#pragma unroll
  for (int j = 0; j < 16; j++) tmp[j] = f2b(tilebuf[kb + j][n]);
  u16* dst = Wt + (size_t)(n0 + n) * K + k0 + kb;
  *(uint4*)dst = *(uint4*)tmp;
  *(uint4*)(dst + 8) = *(uint4*)(tmp + 8);
}

// ---------------------------------------------------------------------------
// Standalone weight transpose (fp32 [K][N] -> bf16 [N][K]) for Wout.
// ---------------------------------------------------------------------------
__global__ __launch_bounds__(256) void transpose_w_kernel(
    const float* __restrict__ W, u16* __restrict__ Wt, int K, int N) {
  __shared__ float tile[64][65];
  int n0 = blockIdx.x * 64, k0 = blockIdx.y * 64;
  int t = threadIdx.x;
  int kr = t >> 4;
  int nc = (t & 15) * 4;
#pragma unroll
  for (int i = 0; i < 4; i++) {
    float4 v = *(const float4*)(W + (size_t)(k0 + kr + i * 16) * N + n0 + nc);
    tile[kr + i * 16][nc] = v.x; tile[kr + i * 16][nc + 1] = v.y;
    tile[kr + i * 16][nc + 2] = v.z; tile[kr + i * 16][nc + 3] = v.w;
  }
  __syncthreads();
  int n = t >> 2;
  int kb = (t & 3) * 16;
  u16 tmp[16];
#pragma unroll
  for (int j = 0; j < 16; j++) tmp[j] = f2b(tile[kb + j][n]);
  u16* dst = Wt + (size_t)(n0 + n) * K + k0 + kb;
  *(uint4*)dst = *(uint4*)tmp;
  *(uint4*)(dst + 8) = *(uint4*)(tmp + 8);
}

// ---------------------------------------------------------------------------
// bf16 MFMA GEMM (generic): C = A(MxK, lda) @ Bt(NxK)^T [+bias][+res][relu]
// 128x128 tile, register-prefetch double-buffer, LDS-staged epilogue.
// ---------------------------------------------------------------------------
template <bool BIAS, bool RES, bool RELU, bool WR32, bool WR16>
__global__ __launch_bounds__(256) void gemm16_kernel(
    const u16* __restrict__ A, const u16* __restrict__ Bt,
    const float* __restrict__ bias, const float* __restrict__ res,
    float* __restrict__ C, u16* __restrict__ C16,
    int M, int N, int K, int lda, int ldc) {
  __shared__ char smem[32768];
  u16* As = (u16*)smem;
  u16* Bs = (u16*)(smem + 16384);
  const int tid = threadIdx.x;
  const int lane = tid & 63;
  const int wv = tid >> 6;
  const int wr = wv >> 1, wc = wv & 1;
  const int m0 = blockIdx.y * 128, n0 = blockIdx.x * 128;

  f32x4 acc[4][4];
#pragma unroll
  for (int i = 0; i < 4; i++)
#pragma unroll
    for (int j = 0; j < 4; j++)
#pragma unroll
      for (int e = 0; e < 4; e++) acc[i][j][e] = 0.0f;

  const int srow = tid >> 3;                 // 0..31
  const int sslot = tid & 7;                 // 16B chunk in 64-elem row
  const int csw = sslot ^ (srow & 7);        // XOR swizzle
  const int fr = lane & 15, kq = lane >> 4, sx = lane & 7;

  uint4 ar[4], br[4];
  const u16* Arow = A + (size_t)(m0 + srow) * lda + sslot * 8;
  const u16* Brow = Bt + (size_t)(n0 + srow) * K + sslot * 8;
#pragma unroll
  for (int i = 0; i < 4; i++) {
    ar[i] = *(const uint4*)(Arow + (size_t)(i * 32) * lda);
    br[i] = *(const uint4*)(Brow + (size_t)(i * 32) * K);
  }

  for (int kt = 0; kt < K; kt += 64) {
    __syncthreads();
#pragma unroll
    for (int i = 0; i < 4; i++) {
      *(uint4*)(As + (srow + i * 32) * 64 + csw * 8) = ar[i];
      *(uint4*)(Bs + (srow + i * 32) * 64 + csw * 8) = br[i];
    }
    __syncthreads();
    if (kt + 64 < K) {
#pragma unroll
      for (int i = 0; i < 4; i++) {
        ar[i] = *(const uint4*)(Arow + (size_t)(i * 32) * lda + (kt + 64));
        br[i] = *(const uint4*)(Brow + (size_t)(i * 32) * K + (kt + 64));
      }
    }
#pragma unroll
    for (int ks = 0; ks < 2; ks++) {
      bf16x8 af[4], bfr[4];
#pragma unroll
      for (int i = 0; i < 4; i++) {
        int rA = wr * 64 + i * 16 + fr;
        af[i] = *(const bf16x8*)(As + rA * 64 + (((ks * 4 + kq) ^ sx) * 8));
        int rB = wc * 64 + i * 16 + fr;
        bfr[i] = *(const bf16x8*)(Bs + rB * 64 + (((ks * 4 + kq) ^ sx) * 8));
      }
#pragma unroll
      for (int mi = 0; mi < 4; mi++)
#pragma unroll
        for (int ni = 0; ni < 4; ni++)
          acc[mi][ni] = __builtin_amdgcn_mfma_f32_16x16x32_bf16(bfr[ni], af[mi], acc[mi][ni], 0, 0, 0);
    }
  }

  // ---- LDS-staged epilogue: full-line cooperative stores ----
  constexpr int CST = 132;
  float* cst = (float*)smem;
  const int rl = lane & 15, cg = (lane >> 4) * 4;
  const int erow = tid >> 5;
  const int ecol = (tid & 31) * 4;
  __syncthreads();
#pragma unroll
  for (int mi = 0; mi < 4; mi++) {
#pragma unroll
    for (int ni = 0; ni < 4; ni++)
      *(f32x4*)&cst[(wr * 16 + rl) * CST + wc * 64 + ni * 16 + cg] = acc[mi][ni];
    __syncthreads();
#pragma unroll
    for (int it = 0; it < 4; it++) {
      int lrow = it * 8 + erow;
      int grow = m0 + mi * 16 + (lrow & 15) + (lrow >> 4) * 64;
      int gcol = n0 + ecol;
      size_t gbase = (size_t)grow * ldc + gcol;
      f32x4 v = *(f32x4*)&cst[lrow * CST + ecol];
      if (BIAS) {
        float4 b4 = *(const float4*)(bias + gcol);
        v[0] += b4.x; v[1] += b4.y; v[2] += b4.z; v[3] += b4.w;
      }
      if (RES) {
        float4 r4 = *(const float4*)(res + gbase);
        v[0] += r4.x; v[1] += r4.y; v[2] += r4.z; v[3] += r4.w;
      }
      if (RELU) {
        v[0] = fmaxf(v[0], 0.f); v[1] = fmaxf(v[1], 0.f);
        v[2] = fmaxf(v[2], 0.f); v[3] = fmaxf(v[3], 0.f);
      }
      if (WR32) *(f32x4*)(C + gbase) = v;
      if (WR16) {
        uint2 p;
        p.x = (u32)f2b(v[0]) | ((u32)f2b(v[1]) << 16);
        p.y = (u32)f2b(v[2]) | ((u32)f2b(v[3]) << 16);
        *(uint2*)(C16 + gbase) = p;
      }
    }
    __syncthreads();
  }
}

// ---------------------------------------------------------------------------
// Logits GEMM: C = A(2048x512)bf16 @ WoutT(32000x512)bf16^T, fp32 out.
// gemm16's proven 0-conflict K-loop (BK=64, [128][64] tiles, XOR swizzle),
// NO register prefetch (R14: prefetch's occupancy cost nets negative),
// 4 waves x (64x64) quadrants, acc[4][4]; 1D XCD-chunked grid; NT epilogue.
// Same k-order and f2b values as the fp32-direct version -> bit-identical.
// ---------------------------------------------------------------------------
__global__ __launch_bounds__(256, 3) void gemm_logits_kernel(
    const u16* __restrict__ A, const u16* __restrict__ Bt,
    float* __restrict__ C, int M, int N, int K, int nby) {
  __shared__ char smem[32768];
  u16* As = (u16*)smem;              // [128][64] 16 KB
  u16* Bs = (u16*)(smem + 16384);    // [128][64] 16 KB
  const int tid = threadIdx.x;
  const int lane = tid & 63;
  const int wvid = tid >> 6;
  const int wr = wvid >> 1, wc = wvid & 1;   // wave -> 64x64 quadrant
  const int per = gridDim.x >> 3;    // gridDim.x % 8 == 0
  const int lbid = (blockIdx.x & 7) * per + (blockIdx.x >> 3);
  const int bx = lbid / nby, by = lbid % nby;
  const int m0 = by * 128, n0 = bx * 128;

  f32x4 acc[4][4];
#pragma unroll
  for (int i = 0; i < 4; i++)
#pragma unroll
    for (int j = 0; j < 4; j++)
#pragma unroll
      for (int e = 0; e < 4; e++) acc[i][j][e] = 0.0f;

  const int srow = tid >> 3;                 // 0..31
  const int sslot = tid & 7;                 // 16B chunk in 64-elem row
  const int csw = sslot ^ (srow & 7);        // XOR swizzle (0-conflict, gemm16)
  const int fr = lane & 15, kq = lane >> 4, sx = lane & 7;
  const u16* Arow = A + (size_t)(m0 + srow) * K + sslot * 8;
  const u16* Brow = Bt + (size_t)(n0 + srow) * K + sslot * 8;

  for (int kt = 0; kt < K; kt += 64) {
    uint4 ar[4], br[4];
#pragma unroll
    for (int i = 0; i < 4; i++) {
      ar[i] = *(const uint4*)(Arow + (size_t)(i * 32) * K + kt);
      br[i] = *(const uint4*)(Brow + (size_t)(i * 32) * K + kt);
    }
    __syncthreads();                 // prior tile's ds_reads done
#pragma unroll
    for (int i = 0; i < 4; i++) {
      *(uint4*)(As + (srow + i * 32) * 64 + csw * 8) = ar[i];
      *(uint4*)(Bs + (srow + i * 32) * 64 + csw * 8) = br[i];
    }
    __syncthreads();                 // LDS visible
#pragma unroll
    for (int ks = 0; ks < 2; ks++) {
      bf16x8 bfr[4];
#pragma unroll
      for (int ni = 0; ni < 4; ni++) {
        int rB = wc * 64 + ni * 16 + fr;
        bfr[ni] = *(const bf16x8*)(Bs + rB * 64 + (((ks * 4 + kq) ^ sx) * 8));
      }
#pragma unroll
      for (int mi = 0; mi < 4; mi++) {
        int rA = wr * 64 + mi * 16 + fr;
        bf16x8 af = *(const bf16x8*)(As + rA * 64 + (((ks * 4 + kq) ^ sx) * 8));
#pragma unroll
        for (int ni = 0; ni < 4; ni++)
          acc[mi][ni] = __builtin_amdgcn_mfma_f32_16x16x32_bf16(bfr[ni], af, acc[mi][ni], 0, 0, 0);
      }
    }
  }

  // ---- epilogue: 4 passes of 32 rows; 512B contiguous per instruction ----
  constexpr int CST = 132;
  float* cst = (float*)smem;         // [32][132] = 16896 B
  const int rl = lane & 15, cg = (lane >> 4) * 4;
  const int erow = tid >> 5;         // 0..7
  const int ecol = (tid & 31) * 4;   // 0..124
  __syncthreads();
#pragma unroll
  for (int mi = 0; mi < 4; mi++) {
#pragma unroll
    for (int ni = 0; ni < 4; ni++)
      *(f32x4*)&cst[(wr * 16 + rl) * CST + wc * 64 + ni * 16 + cg] = acc[mi][ni];
    __syncthreads();
#pragma unroll
    for (int it = 0; it < 4; it++) {
      int lrow = it * 8 + erow;
      int grow = m0 + mi * 16 + (lrow & 15) + (lrow >> 4) * 64;
      size_t gbase = (size_t)grow * N + n0 + ecol;
      f32x4 v = *(f32x4*)&cst[lrow * CST + ecol];
      __builtin_nontemporal_store(v, (f32x4*)(C + gbase));
    }
    __syncthreads();
  }
}

// ---------------------------------------------------------------------------
// RoPE in-place on kd columns (512..1023) of fused qkv buffer (stride QKVW)
// ---------------------------------------------------------------------------
__global__ void rope_kernel(float* __restrict__ qkv) {
  int idx = blockIdx.x * blockDim.x + threadIdx.x;
  if (idx >= Bn * Sn * Hn * (ROTn / 2)) return;
  int i = idx & 15;
  int h = (idx >> 4) & (Hn - 1);
  int s = (idx >> 7) & (Sn - 1);
  int b = idx >> 17;
  float inv = powf(10000.0f, -(float)(2 * i) / (float)ROTn);
  float ang = (float)s * inv;
  float c = cosf(ang), sn = sinf(ang);
  float* p = qkv + (size_t)(b * Sn + s) * QKVW + 512 + h * DHn + 2 * i;
  float k1 = p[0], k2 = p[1];
  p[0] = k1 * c - k2 * sn;
  p[1] = k2 * c + k1 * sn;
}

// ---------------------------------------------------------------------------
// down + max + w = exp(down - max); kd at qkv cols 512.., stride QKVW
// ---------------------------------------------------------------------------
__global__ __launch_bounds__(256) void down_w_kernel(
    const float* __restrict__ q_down, const float* __restrict__ qkv,
    float* __restrict__ w) {
  int bid = blockIdx.x;
  int c = bid % Cn;
  int h = (bid / Cn) % Hn;
  int b = bid / (Cn * Hn);
  int tid = threadIdx.x;
  __shared__ float qv[DHn];
  __shared__ float red[256];
  if (tid < DHn) qv[tid] = q_down[(size_t)c * Dn + h * DHn + tid] * SCALE;
  __syncthreads();
  float dn[4];
  float lmax = -1e30f;
  for (int it = 0; it < 4; it++) {
    int s = tid + it * 256;
    const float* kp = qkv + (size_t)(b * Sn + s) * QKVW + 512 + h * DHn;
    float acc = 0.f;
#pragma unroll
    for (int d = 0; d < DHn; d += 4) {
      float4 kv = *(const float4*)(kp + d);
      acc += qv[d] * kv.x + qv[d + 1] * kv.y + qv[d + 2] * kv.z + qv[d + 3] * kv.w;
    }
    dn[it] = acc;
    lmax = fmaxf(lmax, acc);
  }
  red[tid] = lmax;
  __syncthreads();
  for (int st = 128; st > 0; st >>= 1) { if (tid < st) red[tid] = fmaxf(red[tid], red[tid + st]); __syncthreads(); }
  float mx = red[0];
  float* wp = w + (size_t)bid * Sn;
  for (int it = 0; it < 4; it++) wp[tid + it * 256] = expf(dn[it] - mx);
}

// ---------------------------------------------------------------------------
// Phase 1: per-chunk totals. vkv layout [row][1024] = [vdk(512)|vdv(512)]
// ---------------------------------------------------------------------------
__global__ __launch_bounds__(256) void chunk_sums_kernel(
    const float* __restrict__ w, const float* __restrict__ vkv,
    float* __restrict__ chunkT) {
  int bid = blockIdx.x;
  int ch = bid % NCH;
  int h = (bid / NCH) % Hn;
  int b = bid / (NCH * Hn);
  int tid = threadIdx.x;
  int s0 = ch * CSs;
  __shared__ float vch[CSs][128];
  __shared__ float wch[Cn][CSs + 1];
#pragma unroll
  for (int i = 0; i < 4; i++) {
    int v = tid + i * 256;
    int t = v >> 5, dv = v & 31;
    int col = (dv < 16) ? (h * DHn + dv * 4) : (512 + h * DHn + (dv - 16) * 4);
    *(float4*)&vch[t][dv * 4] = *(const float4*)(vkv + (size_t)(b * Sn + s0 + t) * KVW + col);
  }
  for (int v = tid; v < Cn * CSs; v += 256) {
    int cc = v >> 5, t = v & 31;
    wch[cc][t] = w[((size_t)((b * Hn + h) * Cn + cc)) * Sn + s0 + t];
  }
  __syncthreads();
  int c = tid & 63, q = tid >> 6;
  float acc[32] = {};
  float nsum = 0.f;
  for (int t = 0; t < CSs; t++) {
    float wv = wch[c][t];
    nsum += wv;
#pragma unroll
    for (int j = 0; j < 8; j++) {
      float4 vv = *(float4*)&vch[t][q * 32 + j * 4];
      acc[j * 4 + 0] += wv * vv.x; acc[j * 4 + 1] += wv * vv.y;
      acc[j * 4 + 2] += wv * vv.z; acc[j * 4 + 3] += wv * vv.w;
    }
  }
  float* dst = chunkT + ((size_t)(((b * Hn + h) * Cn + c) * NCH + ch)) * 132;
#pragma unroll
  for (int j = 0; j < 8; j++) {
    float4 o; o.x = acc[j*4]; o.y = acc[j*4+1]; o.z = acc[j*4+2]; o.w = acc[j*4+3];
    *(float4*)(dst + q * 32 + j * 4) = o;
  }
  if (q == 0) dst[128] = nsum;
}

// Phase 2: exclusive scan over chunks
__global__ void scan_chunks_kernel(float* __restrict__ chunkT) {
  int tid = threadIdx.x;
  if (tid >= 129) return;
  size_t base = (size_t)blockIdx.x * NCH * 132 + tid;
  float run = 0.f;
  for (int ch = 0; ch < NCH; ch++) {
    float v = chunkT[base + (size_t)ch * 132];
    chunkT[base + (size_t)ch * 132] = run;
    run += v;
  }
}

// ---------------------------------------------------------------------------
// Phase 3: inclusive scan fused with up-dot, softmax over C, PV; bf16 out.
// 2 barriers per t; softmax computed redundantly by ALL waves (lane == c).
// ---------------------------------------------------------------------------
__global__ __launch_bounds__(256) void attn_scan_kernel(
    const float* __restrict__ w, const float* __restrict__ vkv,
    const float* __restrict__ qkv, const float* __restrict__ chunkT,
    u16* __restrict__ ao16) {
  int bid = blockIdx.x;
  int ch = bid % NCH;
  int h = (bid / NCH) % Hn;
  int b = bid / (NCH * Hn);
  int tid = threadIdx.x;
  int c = tid & 63, q = tid >> 6;
  int s0 = ch * CSs;

  __shared__ float vch[CSs][128];
  __shared__ float wch[CSs][Cn + 1];
  __shared__ float qch[CSs][DHn];
  __shared__ float red[Cn][2];
  __shared__ float mres[Cn][DHn + 1];

#pragma unroll
  for (int i = 0; i < 4; i++) {
    int v = tid + i * 256;
    int t = v >> 5, dv = v & 31;
    int col = (dv < 16) ? (h * DHn + dv * 4) : (512 + h * DHn + (dv - 16) * 4);
    *(float4*)&vch[t][dv * 4] = *(const float4*)(vkv + (size_t)(b * Sn + s0 + t) * KVW + col);
  }
  for (int v = tid; v < CSs * DHn; v += 256) {
    int t = v >> 6, d = v & 63;
    qch[t][d] = qkv[(size_t)(b * Sn + s0 + t) * QKVW + h * DHn + d];
  }
  for (int v = tid; v < Cn * CSs; v += 256) {
    int cc = v >> 5, t = v & 31;
    wch[t][cc] = w[((size_t)((b * Hn + h) * Cn + cc)) * Sn + s0 + t];
  }
  const float* pre = chunkT + ((size_t)(((b * Hn + h) * Cn + c) * NCH + ch)) * 132;
  float acc[32];
#pragma unroll
  for (int j = 0; j < 8; j++) {
    float4 vv = *(const float4*)(pre + q * 32 + j * 4);
    acc[j * 4 + 0] = vv.x; acc[j * 4 + 1] = vv.y; acc[j * 4 + 2] = vv.z; acc[j * 4 + 3] = vv.w;
  }
  float norm = pre[128];
  __syncthreads();

  for (int t = 0; t < CSs; t++) {
    float wv = wch[t][c];
    norm += wv;
#pragma unroll
    for (int j = 0; j < 8; j++) {
      float4 vv = *(const float4*)&vch[t][q * 32 + j * 4];
      acc[j * 4 + 0] += wv * vv.x; acc[j * 4 + 1] += wv * vv.y;
      acc[j * 4 + 2] += wv * vv.z; acc[j * 4 + 3] += wv * vv.w;
    }
    if (q < 2) {
      float pd = 0.f;
#pragma unroll
      for (int j = 0; j < 8; j++) {
        float4 qv = *(const float4*)&qch[t][q * 32 + j * 4];
        pd += qv.x * acc[j * 4] + qv.y * acc[j * 4 + 1] + qv.z * acc[j * 4 + 2] + qv.w * acc[j * 4 + 3];
      }
      red[c][q] = pd;
    }
    __syncthreads();                               // B1: red visible
    float u = (red[c][0] + red[c][1]) * SCALE / norm;
    float mx = u;
#pragma unroll
    for (int m = 32; m >= 1; m >>= 1) mx = fmaxf(mx, __shfl_xor(mx, m));
    float e = expf(u - mx);
    float sm = e;
#pragma unroll
    for (int m = 32; m >= 1; m >>= 1) sm += __shfl_xor(sm, m);
    float pp = e / (sm * norm);
    if (q >= 2) {
#pragma unroll
      for (int j = 0; j < 32; j++) mres[c][(q - 2) * 32 + j] = pp * acc[j];
    }
    __syncthreads();                               // B2: mres visible
    if (tid < 64) {
      float o = 0.f;
#pragma unroll
      for (int cc = 0; cc < 64; cc++) o += mres[cc][tid];
      ao16[(size_t)(b * Sn + s0 + t) * Dn + h * DHn + tid] = f2b(o);
    }
  }
}

// ---------------------------------------------------------------------------
extern "C" void kernel_launch(void* const* d_in, const int* in_sizes, int n_in,
                              void* d_out, int out_size, void* d_ws, size_t ws_size,
                              hipStream_t stream) {
  (void)in_sizes; (void)n_in; (void)out_size; (void)ws_size;
  const int*   tokens = (const int*)d_in[0];
  const float* emb    = (const float*)d_in[1];
  const float* ln1_g  = (const float*)d_in[2];
  const float* ln1_b  = (const float*)d_in[3];
  const float* q_down = (const float*)d_in[4];
  const float* Wq     = (const float*)d_in[5];
  const float* bq     = (const float*)d_in[6];
  const float* Wk     = (const float*)d_in[7];
  const float* bk     = (const float*)d_in[8];
  const float* Wv     = (const float*)d_in[9];
  const float* bv     = (const float*)d_in[10];
  const float* Wo     = (const float*)d_in[11];
  const float* bo     = (const float*)d_in[12];
  const float* ln2_g  = (const float*)d_in[13];
  const float* ln2_b  = (const float*)d_in[14];
  const float* W1     = (const float*)d_in[15];
  const float* b1     = (const float*)d_in[16];
  const float* W2     = (const float*)d_in[17];
  const float* b2     = (const float*)d_in[18];
  const float* lnf_g  = (const float*)d_in[19];
  const float* lnf_b  = (const float*)d_in[20];
  const float* Wout   = (const float*)d_in[21];
  float* out = (float*)d_out;

  float* ws = (float*)d_ws;
  // layout (floats)
  float* qkv   = ws;                                   // 3,145,728  [2048][1536]
  u16*   qkv16 = (u16*)(ws + 3145728);                 //   786,432
  float* vkv   = ws + 3932160;                         // 2,097,152  [2048][1024]
  float* w     = ws + 6029312;                         // 1,048,576
  float* chunk = ws + 7077888;                         // 4,325,376
  float* h     = ws + 11403264;                        // 1,048,576
  u16*   h16   = (u16*)(ws + 12451840);                //   524,288
  u16*   ao16  = (u16*)(ws + 12976128);                //   524,288 (later xf16)
  float* a     = ws + 13500416;                        // 1,048,576 (later x3)
  float* x2    = ws + 14548992;                        // 1,048,576
  u16*   x216  = (u16*)(ws + 15597568);                //   524,288
  u16*   ff116 = (u16*)(ws + 16121856);                // 1,048,576
  u16*   WqkvT = (u16*)(ws + 17170432);                //   393,216  [1536][512]
  u16*   WoT   = (u16*)(ws + 17563648);                //   131,072
  u16*   W1T   = (u16*)(ws + 17694720);                //   262,144
  u16*   W2T   = (u16*)(ws + 17956864);                //   262,144
  // aliases into dead regions:
  float* bqkv  = chunk;                                // 1536 (dead before chunk_sums)
  u16*   WoutT = (u16*)ws;                             // [32000][512] bf16 = 8.19M floats,
                                                       // aliases qkv..chunk (dead after attn_scan)
  u16*   vd16  = qkv16 + 1024;                         // vd cols in qkv16 (stride QKVW)
  float* x3    = a;                                    // a dead after LN2
  u16*   xf16  = ao16;                                 // ao16 dead after Wo gemm
  float* lnf32 = x2;                                   // x2 dead after W2 gemm

  const int M = Bn * Sn;  // 2048

  // x = emb[tokens]; h = LN1(x) (+bf16)
  embed_ln_kernel<<<M, 256, 0, stream>>>(tokens, emb, ln1_g, ln1_b, h, h16);

  // merged weight prep: 6 transposes + bias concat
  prep_weights_kernel<<<513, 256, 0, stream>>>(
      Wq, Wk, Wv, Wo, W1, W2, WqkvT, WoT, W1T, W2T, bq, bk, bv, bqkv);

  // fused QKV projection: qkv = h @ [Wq|Wk|Wv] + [bq|bk|bv]  (fp32 + bf16)
  gemm16_kernel<true, false, false, true, true>
      <<<dim3(QKVW / 128, M / 128), 256, 0, stream>>>(
      h16, WqkvT, bqkv, nullptr, qkv, qkv16, M, QKVW, Dn, Dn, QKVW);

  rope_kernel<<<(Bn * Sn * Hn * (ROTn / 2) + 255) / 256, 256, 0, stream>>>(qkv);
  down_w_kernel<<<Bn * Hn * Cn, 256, 0, stream>>>(q_down, qkv, w);

  // fused KV-of-vd: vkv = vd @ [Wk|Wv] + [bk|bv]
  gemm16_kernel<true, false, false, true, false>
      <<<dim3(KVW / 128, M / 128), 256, 0, stream>>>(
      vd16, WqkvT + 512 * 512, bqkv + 512, nullptr, vkv, nullptr, M, KVW, Dn, QKVW, KVW);

  // chunked cumulative scan
  chunk_sums_kernel<<<Bn * Hn * NCH, 256, 0, stream>>>(w, vkv, chunk);
  scan_chunks_kernel<<<Bn * Hn * Cn, 192, 0, stream>>>(chunk);
  attn_scan_kernel<<<Bn * Hn * NCH, 256, 0, stream>>>(w, vkv, qkv, chunk, ao16);

  // Wout transpose into dead attention scratch (must be after attn_scan)
  transpose_w_kernel<<<dim3(OUTn / 64, Dn / 64), 256, 0, stream>>>(Wout, WoutT, Dn, OUTn);

  // a = attn @ Wo + bo
  gemm16_kernel<true, false, false, true, false>
      <<<dim3(Dn / 128, M / 128), 256, 0, stream>>>(
      ao16, WoT, bo, nullptr, a, nullptr, M, Dn, Dn, Dn, Dn);

  // x2 = LN2(h + a) (+bf16)
  ln_kernel<<<M, 256, 0, stream>>>(a, h, ln2_g, ln2_b, x2, x216);

  // ff1 = relu(x2 @ W1 + b1) -> bf16 only
  gemm16_kernel<true, false, true, false, true>
      <<<dim3(MLPn / 128, M / 128), 256, 0, stream>>>(
      x216, W1T, b1, nullptr, nullptr, ff116, M, MLPn, Dn, Dn, MLPn);
  // x3 = x2 + ff1 @ W2 + b2
  gemm16_kernel<true, true, false, true, false>
      <<<dim3(Dn / 128, M / 128), 256, 0, stream>>>(
      ff116, W2T, b2, x2, x3, nullptr, M, Dn, MLPn, MLPn, Dn);

  // xf = LNf(x3) -> bf16
  ln_kernel<<<M, 256, 0, stream>>>(x3, nullptr, lnf_g, lnf_b, lnf32, xf16);

  // logits = xf @ WoutT^T  (bf16 both sides, 0-conflict staging; NT stores)
  gemm_logits_kernel<<<dim3((OUTn / 128) * (M / 128), 1), 256, 0, stream>>>(
      xf16, WoutT, out, M, OUTn, Dn, M / 128);
}

// Round 17
// 397.574 us; speedup vs baseline: 1.5897x; 1.5897x over previous
//
#include <hip/hip_runtime.h>
#include <hip/hip_bf16.h>
#include <cstdint>

typedef unsigned short u16;
typedef unsigned int u32;
typedef __bf16 bf16_t;
typedef bf16_t bf16x8 __attribute__((ext_vector_type(8)));
typedef float f32x4 __attribute__((ext_vector_type(4)));

// Problem constants
constexpr int Bn = 2, Sn = 1024, Dn = 512, Hn = 8, Cn = 64, DHn = 64, ROTn = 32;
constexpr int MLPn = 1024, OUTn = 32000;
constexpr int NCH = 32;
constexpr int CSs = Sn / NCH;
constexpr float SCALE = 0.125f;
constexpr float EPSf = 1e-5f;
constexpr int QKVW = 1536;   // fused qkv row width
constexpr int KVW = 1024;    // fused vdk|vdv row width

__device__ __forceinline__ u16 f2b(float x) {  // fp32 -> bf16 bits, RNE
  u32 u = __float_as_uint(x);
  u32 r = (u + 0x7FFFu + ((u >> 16) & 1u)) >> 16;
  return (u16)r;
}

// ---------------------------------------------------------------------------
// Embedding gather + LayerNorm; writes fp32 and bf16
// ---------------------------------------------------------------------------
__global__ __launch_bounds__(256) void embed_ln_kernel(
    const int* __restrict__ tokens, const float* __restrict__ emb,
    const float* __restrict__ g, const float* __restrict__ bb,
    float* __restrict__ out, u16* __restrict__ out16) {
  int row = blockIdx.x;
  int tid = threadIdx.x;
  int tok = tokens[row];
  const float* src = emb + (size_t)tok * Dn;
  __shared__ float red[256];
  float v0 = src[tid], v1 = src[tid + 256];
  red[tid] = v0 + v1;
  __syncthreads();
  for (int s = 128; s > 0; s >>= 1) { if (tid < s) red[tid] += red[tid + s]; __syncthreads(); }
  float mean = red[0] * (1.0f / Dn);
  __syncthreads();
  float d0 = v0 - mean, d1 = v1 - mean;
  red[tid] = d0 * d0 + d1 * d1;
  __syncthreads();
  for (int s = 128; s > 0; s >>= 1) { if (tid < s) red[tid] += red[tid + s]; __syncthreads(); }
  float rstd = rsqrtf(red[0] * (1.0f / Dn) + EPSf);
  float o0 = d0 * rstd * g[tid] + bb[tid];
  float o1 = d1 * rstd * g[tid + 256] + bb[tid + 256];
  float* dst = out + (size_t)row * Dn;
  dst[tid] = o0; dst[tid + 256] = o1;
  u16* dst16 = out16 + (size_t)row * Dn;
  dst16[tid] = f2b(o0); dst16[tid + 256] = f2b(o1);
}

// LayerNorm of (x [+ res]) -> out (fp32) and out16 (bf16, optional)
__global__ __launch_bounds__(256) void ln_kernel(
    const float* __restrict__ x, const float* __restrict__ res,
    const float* __restrict__ g, const float* __restrict__ bb,
    float* __restrict__ out, u16* __restrict__ out16) {
  int row = blockIdx.x;
  int tid = threadIdx.x;
  const float* xr = x + (size_t)row * Dn;
  float v0 = xr[tid], v1 = xr[tid + 256];
  if (res) {
    const float* rr = res + (size_t)row * Dn;
    v0 += rr[tid]; v1 += rr[tid + 256];
  }
  __shared__ float red[256];
  red[tid] = v0 + v1;
  __syncthreads();
  for (int s = 128; s > 0; s >>= 1) { if (tid < s) red[tid] += red[tid + s]; __syncthreads(); }
  float mean = red[0] * (1.0f / Dn);
  __syncthreads();
  float d0 = v0 - mean, d1 = v1 - mean;
  red[tid] = d0 * d0 + d1 * d1;
  __syncthreads();
  for (int s = 128; s > 0; s >>= 1) { if (tid < s) red[tid] += red[tid + s]; __syncthreads(); }
  float rstd = rsqrtf(red[0] * (1.0f / Dn) + EPSf);
  float o0 = d0 * rstd * g[tid] + bb[tid];
  float o1 = d1 * rstd * g[tid + 256] + bb[tid + 256];
  float* dst = out + (size_t)row * Dn;
  dst[tid] = o0; dst[tid + 256] = o1;
  if (out16) {
    u16* dst16 = out16 + (size_t)row * Dn;
    dst16[tid] = f2b(o0); dst16[tid + 256] = f2b(o1);
  }
}

// ---------------------------------------------------------------------------
// Merged weight prep: 6 transposes (fp32 [K][N] -> bf16 [N][K]) + bias concat.
// ---------------------------------------------------------------------------
__global__ __launch_bounds__(256) void prep_weights_kernel(
    const float* __restrict__ Wq, const float* __restrict__ Wk,
    const float* __restrict__ Wv, const float* __restrict__ Wo,
    const float* __restrict__ W1, const float* __restrict__ W2,
    u16* __restrict__ WqkvT, u16* __restrict__ WoT,
    u16* __restrict__ W1T, u16* __restrict__ W2T,
    const float* __restrict__ bq, const float* __restrict__ bk,
    const float* __restrict__ bv, float* __restrict__ bqkv) {
  int bid = blockIdx.x;
  int t = threadIdx.x;
  if (bid == 512) {
    for (int i = t; i < 512; i += 256) {
      bqkv[i] = bq[i]; bqkv[512 + i] = bk[i]; bqkv[1024 + i] = bv[i];
    }
    return;
  }
  const float* W; u16* Wt; int K, N, tile, nbx;
  if (bid < 64)       { W = Wq; Wt = WqkvT;              K = 512;  N = 512;  tile = bid;       nbx = 8;  }
  else if (bid < 128) { W = Wk; Wt = WqkvT + 512 * 512;  K = 512;  N = 512;  tile = bid - 64;  nbx = 8;  }
  else if (bid < 192) { W = Wv; Wt = WqkvT + 1024 * 512; K = 512;  N = 512;  tile = bid - 128; nbx = 8;  }
  else if (bid < 256) { W = Wo; Wt = WoT;                K = 512;  N = 512;  tile = bid - 192; nbx = 8;  }
  else if (bid < 384) { W = W1; Wt = W1T;                K = 512;  N = 1024; tile = bid - 256; nbx = 16; }
  else                { W = W2; Wt = W2T;                K = 1024; N = 512;  tile = bid - 384; nbx = 8;  }
  int n0 = (tile % nbx) * 64, k0 = (tile / nbx) * 64;

  __shared__ float tilebuf[64][65];
  int kr = t >> 4;
  int nc = (t & 15) * 4;
#pragma unroll
  for (int i = 0; i < 4; i++) {
    float4 v = *(const float4*)(W + (size_t)(k0 + kr + i * 16) * N + n0 + nc);
    tilebuf[kr + i * 16][nc] = v.x; tilebuf[kr + i * 16][nc + 1] = v.y;
    tilebuf[kr + i * 16][nc + 2] = v.z; tilebuf[kr + i * 16][nc + 3] = v.w;
  }
  __syncthreads();
  int n = t >> 2;
  int kb = (t & 3) * 16;
  u16 tmp[16];
#pragma unroll
  for (int j = 0; j < 16; j++) tmp[j] = f2b(tilebuf[kb + j][n]);
  u16* dst = Wt + (size_t)(n0 + n) * K + k0 + kb;
  *(uint4*)dst = *(uint4*)tmp;
  *(uint4*)(dst + 8) = *(uint4*)(tmp + 8);
}

// ---------------------------------------------------------------------------
// bf16 MFMA GEMM (generic): C = A(MxK, lda) @ Bt(NxK)^T [+bias][+res][relu]
// 128x128 tile, register-prefetch double-buffer, LDS-staged epilogue.
// ---------------------------------------------------------------------------
template <bool BIAS, bool RES, bool RELU, bool WR32, bool WR16>
__global__ __launch_bounds__(256) void gemm16_kernel(
    const u16* __restrict__ A, const u16* __restrict__ Bt,
    const float* __restrict__ bias, const float* __restrict__ res,
    float* __restrict__ C, u16* __restrict__ C16,
    int M, int N, int K, int lda, int ldc) {
  __shared__ char smem[32768];
  u16* As = (u16*)smem;
  u16* Bs = (u16*)(smem + 16384);
  const int tid = threadIdx.x;
  const int lane = tid & 63;
  const int wv = tid >> 6;
  const int wr = wv >> 1, wc = wv & 1;
  const int m0 = blockIdx.y * 128, n0 = blockIdx.x * 128;

  f32x4 acc[4][4];
#pragma unroll
  for (int i = 0; i < 4; i++)
#pragma unroll
    for (int j = 0; j < 4; j++)
#pragma unroll
      for (int e = 0; e < 4; e++) acc[i][j][e] = 0.0f;

  const int srow = tid >> 3;                 // 0..31
  const int sslot = tid & 7;                 // 16B chunk in 64-elem row
  const int csw = sslot ^ (srow & 7);        // XOR swizzle
  const int fr = lane & 15, kq = lane >> 4, sx = lane & 7;

  uint4 ar[4], br[4];
  const u16* Arow = A + (size_t)(m0 + srow) * lda + sslot * 8;
  const u16* Brow = Bt + (size_t)(n0 + srow) * K + sslot * 8;
#pragma unroll
  for (int i = 0; i < 4; i++) {
    ar[i] = *(const uint4*)(Arow + (size_t)(i * 32) * lda);
    br[i] = *(const uint4*)(Brow + (size_t)(i * 32) * K);
  }

  for (int kt = 0; kt < K; kt += 64) {
    __syncthreads();
#pragma unroll
    for (int i = 0; i < 4; i++) {
      *(uint4*)(As + (srow + i * 32) * 64 + csw * 8) = ar[i];
      *(uint4*)(Bs + (srow + i * 32) * 64 + csw * 8) = br[i];
    }
    __syncthreads();
    if (kt + 64 < K) {
#pragma unroll
      for (int i = 0; i < 4; i++) {
        ar[i] = *(const uint4*)(Arow + (size_t)(i * 32) * lda + (kt + 64));
        br[i] = *(const uint4*)(Brow + (size_t)(i * 32) * K + (kt + 64));
      }
    }
#pragma unroll
    for (int ks = 0; ks < 2; ks++) {
      bf16x8 af[4], bfr[4];
#pragma unroll
      for (int i = 0; i < 4; i++) {
        int rA = wr * 64 + i * 16 + fr;
        af[i] = *(const bf16x8*)(As + rA * 64 + (((ks * 4 + kq) ^ sx) * 8));
        int rB = wc * 64 + i * 16 + fr;
        bfr[i] = *(const bf16x8*)(Bs + rB * 64 + (((ks * 4 + kq) ^ sx) * 8));
      }
#pragma unroll
      for (int mi = 0; mi < 4; mi++)
#pragma unroll
        for (int ni = 0; ni < 4; ni++)
          acc[mi][ni] = __builtin_amdgcn_mfma_f32_16x16x32_bf16(bfr[ni], af[mi], acc[mi][ni], 0, 0, 0);
    }
  }

  // ---- LDS-staged epilogue: full-line cooperative stores ----
  constexpr int CST = 132;
  float* cst = (float*)smem;
  const int rl = lane & 15, cg = (lane >> 4) * 4;
  const int erow = tid >> 5;
  const int ecol = (tid & 31) * 4;
  __syncthreads();
#pragma unroll
  for (int mi = 0; mi < 4; mi++) {
#pragma unroll
    for (int ni = 0; ni < 4; ni++)
      *(f32x4*)&cst[(wr * 16 + rl) * CST + wc * 64 + ni * 16 + cg] = acc[mi][ni];
    __syncthreads();
#pragma unroll
    for (int it = 0; it < 4; it++) {
      int lrow = it * 8 + erow;
      int grow = m0 + mi * 16 + (lrow & 15) + (lrow >> 4) * 64;
      int gcol = n0 + ecol;
      size_t gbase = (size_t)grow * ldc + gcol;
      f32x4 v = *(f32x4*)&cst[lrow * CST + ecol];
      if (BIAS) {
        float4 b4 = *(const float4*)(bias + gcol);
        v[0] += b4.x; v[1] += b4.y; v[2] += b4.z; v[3] += b4.w;
      }
      if (RES) {
        float4 r4 = *(const float4*)(res + gbase);
        v[0] += r4.x; v[1] += r4.y; v[2] += r4.z; v[3] += r4.w;
      }
      if (RELU) {
        v[0] = fmaxf(v[0], 0.f); v[1] = fmaxf(v[1], 0.f);
        v[2] = fmaxf(v[2], 0.f); v[3] = fmaxf(v[3], 0.f);
      }
      if (WR32) *(f32x4*)(C + gbase) = v;
      if (WR16) {
        uint2 p;
        p.x = (u32)f2b(v[0]) | ((u32)f2b(v[1]) << 16);
        p.y = (u32)f2b(v[2]) | ((u32)f2b(v[3]) << 16);
        *(uint2*)(C16 + gbase) = p;
      }
    }
    __syncthreads();
  }
}

// ---------------------------------------------------------------------------
// Logits GEMM (R13 best config — empirical optimum across 9 variants):
// C = A(2048x512)bf16 @ Wout(512x32000)fp32, fp32 out, no bias.
// 128x128 tile, 4 waves x (64x64), acc[4][4]=64 regs, VGPR 52 -> occ ~40%.
// BK=32, 20KB LDS, pad-40 rows. XCD-chunked 1D grid; NT stores.
// fp32-direct W staging keeps HBM pressure ~1.8 TB/s, the benign TCC regime
// (bf16-pretransposed BK=64 variant drove 5.2 TB/s and re-triggered 5x
// fetch+write amplification — R16).
// ---------------------------------------------------------------------------
__global__ __launch_bounds__(256, 3) void gemm_logits_kernel(
    const u16* __restrict__ A, const float* __restrict__ W,
    float* __restrict__ C, int M, int N, int K, int nby) {
  constexpr int BRS = 40;            // padded row stride (bf16 elems), 80B
  __shared__ char smem[20480];
  u16* As = (u16*)smem;              // [128][40] 10240 B
  u16* Bs = (u16*)(smem + 10240);    // [128][40] 10240 B
  const int tid = threadIdx.x;
  const int lane = tid & 63;
  const int wvid = tid >> 6;
  const int wr = wvid >> 1, wc = wvid & 1;   // wave -> 64x64 quadrant
  const int per = gridDim.x >> 3;    // gridDim.x % 8 == 0
  const int lbid = (blockIdx.x & 7) * per + (blockIdx.x >> 3);
  const int bx = lbid / nby, by = lbid % nby;
  const int m0 = by * 128, n0 = bx * 128;

  f32x4 acc[4][4];
#pragma unroll
  for (int i = 0; i < 4; i++)
#pragma unroll
    for (int j = 0; j < 4; j++)
#pragma unroll
      for (int e = 0; e < 4; e++) acc[i][j][e] = 0.0f;

  const int arow = tid >> 1;         // 0..127 (A staging row)
  const int acb = (tid & 1) * 2;     // A chunk base: 0 or 2
  const int wcol = tid & 127;        // W staging column
  const int khalf = tid >> 7;        // 0 or 1: k 0..15 / 16..31
  const int fr = lane & 15, kq = lane >> 4;
  const u16* Ag = A + (size_t)(m0 + arow) * K + acb * 8;
  const float* Wcol = W + n0 + wcol;

  for (int kt = 0; kt < K; kt += 32) {
    uint4 a0 = *(const uint4*)(Ag + kt);
    uint4 a1 = *(const uint4*)(Ag + kt + 8);
    float wld[16];
#pragma unroll
    for (int i = 0; i < 2; i++) {
      const float* wp = Wcol + (size_t)(kt + khalf * 16 + i * 8) * N;
#pragma unroll
      for (int j = 0; j < 8; j++) wld[i * 8 + j] = wp[(size_t)j * N];
    }
    __syncthreads();                 // prior tile's ds_reads done
    *(uint4*)(As + arow * BRS + (acb + 0) * 8) = a0;
    *(uint4*)(As + arow * BRS + (acb + 1) * 8) = a1;
#pragma unroll
    for (int i = 0; i < 2; i++) {
      u16 pk[8];
#pragma unroll
      for (int j = 0; j < 8; j++) pk[j] = f2b(wld[i * 8 + j]);
      *(uint4*)(Bs + wcol * BRS + (khalf * 2 + i) * 8) = *(uint4*)pk;
    }
    __syncthreads();                 // LDS visible
    bf16x8 bfr[4];
#pragma unroll
    for (int ni = 0; ni < 4; ni++)
      bfr[ni] = *(const bf16x8*)(Bs + (wc * 64 + ni * 16 + fr) * BRS + kq * 8);
#pragma unroll
    for (int mi = 0; mi < 4; mi++) {
      bf16x8 af = *(const bf16x8*)(As + (wr * 64 + mi * 16 + fr) * BRS + kq * 8);
#pragma unroll
      for (int ni = 0; ni < 4; ni++)
        acc[mi][ni] = __builtin_amdgcn_mfma_f32_16x16x32_bf16(bfr[ni], af, acc[mi][ni], 0, 0, 0);
    }
  }

  // ---- epilogue: 4 passes of 32 rows; 512B contiguous per instruction ----
  constexpr int CST = 132;
  float* cst = (float*)smem;         // [32][132] = 16896 B
  const int rl = lane & 15, cg = (lane >> 4) * 4;
  const int erow = tid >> 5;         // 0..7
  const int ecol = (tid & 31) * 4;   // 0..124
  __syncthreads();
#pragma unroll
  for (int mi = 0; mi < 4; mi++) {
#pragma unroll
    for (int ni = 0; ni < 4; ni++)
      *(f32x4*)&cst[(wr * 16 + rl) * CST + wc * 64 + ni * 16 + cg] = acc[mi][ni];
    __syncthreads();
#pragma unroll
    for (int it = 0; it < 4; it++) {
      int lrow = it * 8 + erow;
      int grow = m0 + mi * 16 + (lrow & 15) + (lrow >> 4) * 64;
      size_t gbase = (size_t)grow * N + n0 + ecol;
      f32x4 v = *(f32x4*)&cst[lrow * CST + ecol];
      __builtin_nontemporal_store(v, (f32x4*)(C + gbase));
    }
    __syncthreads();
  }
}

// ---------------------------------------------------------------------------
// RoPE in-place on kd columns (512..1023) of fused qkv buffer (stride QKVW)
// ---------------------------------------------------------------------------
__global__ void rope_kernel(float* __restrict__ qkv) {
  int idx = blockIdx.x * blockDim.x + threadIdx.x;
  if (idx >= Bn * Sn * Hn * (ROTn / 2)) return;
  int i = idx & 15;
  int h = (idx >> 4) & (Hn - 1);
  int s = (idx >> 7) & (Sn - 1);
  int b = idx >> 17;
  float inv = powf(10000.0f, -(float)(2 * i) / (float)ROTn);
  float ang = (float)s * inv;
  float c = cosf(ang), sn = sinf(ang);
  float* p = qkv + (size_t)(b * Sn + s) * QKVW + 512 + h * DHn + 2 * i;
  float k1 = p[0], k2 = p[1];
  p[0] = k1 * c - k2 * sn;
  p[1] = k2 * c + k1 * sn;
}

// ---------------------------------------------------------------------------
// down + max + w = exp(down - max); kd at qkv cols 512.., stride QKVW
// ---------------------------------------------------------------------------
__global__ __launch_bounds__(256) void down_w_kernel(
    const float* __restrict__ q_down, const float* __restrict__ qkv,
    float* __restrict__ w) {
  int bid = blockIdx.x;
  int c = bid % Cn;
  int h = (bid / Cn) % Hn;
  int b = bid / (Cn * Hn);
  int tid = threadIdx.x;
  __shared__ float qv[DHn];
  __shared__ float red[256];
  if (tid < DHn) qv[tid] = q_down[(size_t)c * Dn + h * DHn + tid] * SCALE;
  __syncthreads();
  float dn[4];
  float lmax = -1e30f;
  for (int it = 0; it < 4; it++) {
    int s = tid + it * 256;
    const float* kp = qkv + (size_t)(b * Sn + s) * QKVW + 512 + h * DHn;
    float acc = 0.f;
#pragma unroll
    for (int d = 0; d < DHn; d += 4) {
      float4 kv = *(const float4*)(kp + d);
      acc += qv[d] * kv.x + qv[d + 1] * kv.y + qv[d + 2] * kv.z + qv[d + 3] * kv.w;
    }
    dn[it] = acc;
    lmax = fmaxf(lmax, acc);
  }
  red[tid] = lmax;
  __syncthreads();
  for (int st = 128; st > 0; st >>= 1) { if (tid < st) red[tid] = fmaxf(red[tid], red[tid + st]); __syncthreads(); }
  float mx = red[0];
  float* wp = w + (size_t)bid * Sn;
  for (int it = 0; it < 4; it++) wp[tid + it * 256] = expf(dn[it] - mx);
}

// ---------------------------------------------------------------------------
// Phase 1: per-chunk totals. vkv layout [row][1024] = [vdk(512)|vdv(512)]
// ---------------------------------------------------------------------------
__global__ __launch_bounds__(256) void chunk_sums_kernel(
    const float* __restrict__ w, const float* __restrict__ vkv,
    float* __restrict__ chunkT) {
  int bid = blockIdx.x;
  int ch = bid % NCH;
  int h = (bid / NCH) % Hn;
  int b = bid / (NCH * Hn);
  int tid = threadIdx.x;
  int s0 = ch * CSs;
  __shared__ float vch[CSs][128];
  __shared__ float wch[Cn][CSs + 1];
#pragma unroll
  for (int i = 0; i < 4; i++) {
    int v = tid + i * 256;
    int t = v >> 5, dv = v & 31;
    int col = (dv < 16) ? (h * DHn + dv * 4) : (512 + h * DHn + (dv - 16) * 4);
    *(float4*)&vch[t][dv * 4] = *(const float4*)(vkv + (size_t)(b * Sn + s0 + t) * KVW + col);
  }
  for (int v = tid; v < Cn * CSs; v += 256) {
    int cc = v >> 5, t = v & 31;
    wch[cc][t] = w[((size_t)((b * Hn + h) * Cn + cc)) * Sn + s0 + t];
  }
  __syncthreads();
  int c = tid & 63, q = tid >> 6;
  float acc[32] = {};
  float nsum = 0.f;
  for (int t = 0; t < CSs; t++) {
    float wv = wch[c][t];
    nsum += wv;
#pragma unroll
    for (int j = 0; j < 8; j++) {
      float4 vv = *(float4*)&vch[t][q * 32 + j * 4];
      acc[j * 4 + 0] += wv * vv.x; acc[j * 4 + 1] += wv * vv.y;
      acc[j * 4 + 2] += wv * vv.z; acc[j * 4 + 3] += wv * vv.w;
    }
  }
  float* dst = chunkT + ((size_t)(((b * Hn + h) * Cn + c) * NCH + ch)) * 132;
#pragma unroll
  for (int j = 0; j < 8; j++) {
    float4 o; o.x = acc[j*4]; o.y = acc[j*4+1]; o.z = acc[j*4+2]; o.w = acc[j*4+3];
    *(float4*)(dst + q * 32 + j * 4) = o;
  }
  if (q == 0) dst[128] = nsum;
}

// Phase 2: exclusive scan over chunks
__global__ void scan_chunks_kernel(float* __restrict__ chunkT) {
  int tid = threadIdx.x;
  if (tid >= 129) return;
  size_t base = (size_t)blockIdx.x * NCH * 132 + tid;
  float run = 0.f;
  for (int ch = 0; ch < NCH; ch++) {
    float v = chunkT[base + (size_t)ch * 132];
    chunkT[base + (size_t)ch * 132] = run;
    run += v;
  }
}

// ---------------------------------------------------------------------------
// Phase 3: inclusive scan fused with up-dot, softmax over C, PV; bf16 out.
// 2 barriers per t; softmax computed redundantly by ALL waves (lane == c).
// ---------------------------------------------------------------------------
__global__ __launch_bounds__(256) void attn_scan_kernel(
    const float* __restrict__ w, const float* __restrict__ vkv,
    const float* __restrict__ qkv, const float* __restrict__ chunkT,
    u16* __restrict__ ao16) {
  int bid = blockIdx.x;
  int ch = bid % NCH;
  int h = (bid / NCH) % Hn;
  int b = bid / (NCH * Hn);
  int tid = threadIdx.x;
  int c = tid & 63, q = tid >> 6;
  int s0 = ch * CSs;

  __shared__ float vch[CSs][128];
  __shared__ float wch[CSs][Cn + 1];
  __shared__ float qch[CSs][DHn];
  __shared__ float red[Cn][2];
  __shared__ float mres[Cn][DHn + 1];

#pragma unroll
  for (int i = 0; i < 4; i++) {
    int v = tid + i * 256;
    int t = v >> 5, dv = v & 31;
    int col = (dv < 16) ? (h * DHn + dv * 4) : (512 + h * DHn + (dv - 16) * 4);
    *(float4*)&vch[t][dv * 4] = *(const float4*)(vkv + (size_t)(b * Sn + s0 + t) * KVW + col);
  }
  for (int v = tid; v < CSs * DHn; v += 256) {
    int t = v >> 6, d = v & 63;
    qch[t][d] = qkv[(size_t)(b * Sn + s0 + t) * QKVW + h * DHn + d];
  }
  for (int v = tid; v < Cn * CSs; v += 256) {
    int cc = v >> 5, t = v & 31;
    wch[t][cc] = w[((size_t)((b * Hn + h) * Cn + cc)) * Sn + s0 + t];
  }
  const float* pre = chunkT + ((size_t)(((b * Hn + h) * Cn + c) * NCH + ch)) * 132;
  float acc[32];
#pragma unroll
  for (int j = 0; j < 8; j++) {
    float4 vv = *(const float4*)(pre + q * 32 + j * 4);
    acc[j * 4 + 0] = vv.x; acc[j * 4 + 1] = vv.y; acc[j * 4 + 2] = vv.z; acc[j * 4 + 3] = vv.w;
  }
  float norm = pre[128];
  __syncthreads();

  for (int t = 0; t < CSs; t++) {
    float wv = wch[t][c];
    norm += wv;
#pragma unroll
    for (int j = 0; j < 8; j++) {
      float4 vv = *(const float4*)&vch[t][q * 32 + j * 4];
      acc[j * 4 + 0] += wv * vv.x; acc[j * 4 + 1] += wv * vv.y;
      acc[j * 4 + 2] += wv * vv.z; acc[j * 4 + 3] += wv * vv.w;
    }
    if (q < 2) {
      float pd = 0.f;
#pragma unroll
      for (int j = 0; j < 8; j++) {
        float4 qv = *(const float4*)&qch[t][q * 32 + j * 4];
        pd += qv.x * acc[j * 4] + qv.y * acc[j * 4 + 1] + qv.z * acc[j * 4 + 2] + qv.w * acc[j * 4 + 3];
      }
      red[c][q] = pd;
    }
    __syncthreads();                               // B1: red visible
    float u = (red[c][0] + red[c][1]) * SCALE / norm;
    float mx = u;
#pragma unroll
    for (int m = 32; m >= 1; m >>= 1) mx = fmaxf(mx, __shfl_xor(mx, m));
    float e = expf(u - mx);
    float sm = e;
#pragma unroll
    for (int m = 32; m >= 1; m >>= 1) sm += __shfl_xor(sm, m);
    float pp = e / (sm * norm);
    if (q >= 2) {
#pragma unroll
      for (int j = 0; j < 32; j++) mres[c][(q - 2) * 32 + j] = pp * acc[j];
    }
    __syncthreads();                               // B2: mres visible
    if (tid < 64) {
      float o = 0.f;
#pragma unroll
      for (int cc = 0; cc < 64; cc++) o += mres[cc][tid];
      ao16[(size_t)(b * Sn + s0 + t) * Dn + h * DHn + tid] = f2b(o);
    }
  }
}

// ---------------------------------------------------------------------------
extern "C" void kernel_launch(void* const* d_in, const int* in_sizes, int n_in,
                              void* d_out, int out_size, void* d_ws, size_t ws_size,
                              hipStream_t stream) {
  (void)in_sizes; (void)n_in; (void)out_size; (void)ws_size;
  const int*   tokens = (const int*)d_in[0];
  const float* emb    = (const float*)d_in[1];
  const float* ln1_g  = (const float*)d_in[2];
  const float* ln1_b  = (const float*)d_in[3];
  const float* q_down = (const float*)d_in[4];
  const float* Wq     = (const float*)d_in[5];
  const float* bq     = (const float*)d_in[6];
  const float* Wk     = (const float*)d_in[7];
  const float* bk     = (const float*)d_in[8];
  const float* Wv     = (const float*)d_in[9];
  const float* bv     = (const float*)d_in[10];
  const float* Wo     = (const float*)d_in[11];
  const float* bo     = (const float*)d_in[12];
  const float* ln2_g  = (const float*)d_in[13];
  const float* ln2_b  = (const float*)d_in[14];
  const float* W1     = (const float*)d_in[15];
  const float* b1     = (const float*)d_in[16];
  const float* W2     = (const float*)d_in[17];
  const float* b2     = (const float*)d_in[18];
  const float* lnf_g  = (const float*)d_in[19];
  const float* lnf_b  = (const float*)d_in[20];
  const float* Wout   = (const float*)d_in[21];
  float* out = (float*)d_out;

  float* ws = (float*)d_ws;
  // layout (floats)
  float* qkv   = ws;                                   // 3,145,728  [2048][1536]
  u16*   qkv16 = (u16*)(ws + 3145728);                 //   786,432
  float* vkv   = ws + 3932160;                         // 2,097,152  [2048][1024]
  float* w     = ws + 6029312;                         // 1,048,576
  float* chunk = ws + 7077888;                         // 4,325,376
  float* h     = ws + 11403264;                        // 1,048,576
  u16*   h16   = (u16*)(ws + 12451840);                //   524,288
  u16*   ao16  = (u16*)(ws + 12976128);                //   524,288 (later xf16)
  float* a     = ws + 13500416;                        // 1,048,576 (later x3)
  float* x2    = ws + 14548992;                        // 1,048,576
  u16*   x216  = (u16*)(ws + 15597568);                //   524,288
  u16*   ff116 = (u16*)(ws + 16121856);                // 1,048,576
  u16*   WqkvT = (u16*)(ws + 17170432);                //   393,216  [1536][512]
  u16*   WoT   = (u16*)(ws + 17563648);                //   131,072
  u16*   W1T   = (u16*)(ws + 17694720);                //   262,144
  u16*   W2T   = (u16*)(ws + 17956864);                //   262,144
  // aliases into dead regions:
  float* bqkv  = chunk;                                // 1536 (dead before chunk_sums)
  u16*   vd16  = qkv16 + 1024;                         // vd cols in qkv16 (stride QKVW)
  float* x3    = a;                                    // a dead after LN2
  u16*   xf16  = ao16;                                 // ao16 dead after Wo gemm
  float* lnf32 = x2;                                   // x2 dead after W2 gemm

  const int M = Bn * Sn;  // 2048

  // x = emb[tokens]; h = LN1(x) (+bf16)
  embed_ln_kernel<<<M, 256, 0, stream>>>(tokens, emb, ln1_g, ln1_b, h, h16);

  // merged weight prep: 6 transposes + bias concat
  prep_weights_kernel<<<513, 256, 0, stream>>>(
      Wq, Wk, Wv, Wo, W1, W2, WqkvT, WoT, W1T, W2T, bq, bk, bv, bqkv);

  // fused QKV projection: qkv = h @ [Wq|Wk|Wv] + [bq|bk|bv]  (fp32 + bf16)
  gemm16_kernel<true, false, false, true, true>
      <<<dim3(QKVW / 128, M / 128), 256, 0, stream>>>(
      h16, WqkvT, bqkv, nullptr, qkv, qkv16, M, QKVW, Dn, Dn, QKVW);

  rope_kernel<<<(Bn * Sn * Hn * (ROTn / 2) + 255) / 256, 256, 0, stream>>>(qkv);
  down_w_kernel<<<Bn * Hn * Cn, 256, 0, stream>>>(q_down, qkv, w);

  // fused KV-of-vd: vkv = vd @ [Wk|Wv] + [bk|bv]
  gemm16_kernel<true, false, false, true, false>
      <<<dim3(KVW / 128, M / 128), 256, 0, stream>>>(
      vd16, WqkvT + 512 * 512, bqkv + 512, nullptr, vkv, nullptr, M, KVW, Dn, QKVW, KVW);

  // chunked cumulative scan
  chunk_sums_kernel<<<Bn * Hn * NCH, 256, 0, stream>>>(w, vkv, chunk);
  scan_chunks_kernel<<<Bn * Hn * Cn, 192, 0, stream>>>(chunk);
  attn_scan_kernel<<<Bn * Hn * NCH, 256, 0, stream>>>(w, vkv, qkv, chunk, ao16);

  // a = attn @ Wo + bo
  gemm16_kernel<true, false, false, true, false>
      <<<dim3(Dn / 128, M / 128), 256, 0, stream>>>(
      ao16, WoT, bo, nullptr, a, nullptr, M, Dn, Dn, Dn, Dn);

  // x2 = LN2(h + a) (+bf16)
  ln_kernel<<<M, 256, 0, stream>>>(a, h, ln2_g, ln2_b, x2, x216);

  // ff1 = relu(x2 @ W1 + b1) -> bf16 only
  gemm16_kernel<true, false, true, false, true>
      <<<dim3(MLPn / 128, M / 128), 256, 0, stream>>>(
      x216, W1T, b1, nullptr, nullptr, ff116, M, MLPn, Dn, Dn, MLPn);
  // x3 = x2 + ff1 @ W2 + b2
  gemm16_kernel<true, true, false, true, false>
      <<<dim3(Dn / 128, M / 128), 256, 0, stream>>>(
      ff116, W2T, b2, x2, x3, nullptr, M, Dn, MLPn, MLPn, Dn);

  // xf = LNf(x3) -> bf16
  ln_kernel<<<M, 256, 0, stream>>>(x3, nullptr, lnf_g, lnf_b, lnf32, xf16);

  // logits = xf @ Wout  (128x128 tile, 64-acc/lane, occ ~40%; NT stores)
  gemm_logits_kernel<<<dim3((OUTn / 128) * (M / 128), 1), 256, 0, stream>>>(
      xf16, Wout, out, M, OUTn, Dn, M / 128);
}